// Round 16
// baseline (424.884 us; speedup 1.0000x reference)
//
#include <hip/hip_runtime.h>
#include <hip/hip_bf16.h>
#include <stdint.h>

#define N_NODES 100000
#define N_EDGES 3200000
#define DDIM 256
#define NB 782        // ceil(100000 / 128) buckets of 128 dst nodes
#define CAP 4800      // per-bucket slot capacity (mean 4092, sd 64; 11 sigma)
#define BINBLK 4096   // edges per bin role-block
#define OCAP 65536    // overflow list capacity (statistically unreachable)
#define NOFS 132      // per-bucket offset-row stride (ints)
#define LCAP 2432     // per-half LDS record capacity (mean 2046, sd 45; 8.5 sigma)

typedef __attribute__((ext_vector_type(8))) short short8v;
typedef __attribute__((ext_vector_type(4))) float f32x4;

static __device__ __forceinline__ unsigned short f32_to_bf16_rne(float f) {
  unsigned u = __float_as_uint(f);
  unsigned rounded = u + 0x7FFFu + ((u >> 16) & 1u);
  return (unsigned short)(rounded >> 16);
}

static __device__ __forceinline__ float bf16_to_f32(unsigned short h) {
  return __uint_as_float((unsigned)h << 16);
}

static __device__ __forceinline__ float bfLO(unsigned v) { return __uint_as_float(v << 16); }
static __device__ __forceinline__ float bfHI(unsigned v) { return __uint_as_float(v & 0xFFFF0000u); }

// ---------------- Wt[n][k] = W[k][n], bf16 ----------------

__global__ __launch_bounds__(256) void k_cvtW(const float* __restrict__ w,
                                              unsigned short* __restrict__ wt) {
  int i = blockIdx.x * blockDim.x + threadIdx.x;
  int k = i >> 8;
  int n = i & 255;
  wt[(size_t)n * DDIM + k] = f32_to_bf16_rne(w[(size_t)k * DDIM + n]);
}

// ---------------- fused: GEMM blocks (bid&1==0) + bin blocks (bid&1==1) ----
// GEMM: XW = X @ W (bf16 MFMA), fused f32->bf16 A-stage, tile 128x256, BK=64.
// bin: block-level LDS binning into fixed-stride bucket regions.
// Single-use streams (x, edge lists, bin1) use non-temporal hints so L3
// keeps xw resident for k_baggr's random gather.

__global__ __launch_bounds__(512, 2) void k_gb(const float* __restrict__ x,
                                               const unsigned short* __restrict__ wt,
                                               unsigned short* __restrict__ xw,
                                               const int* __restrict__ esrc,
                                               const int* __restrict__ edst,
                                               const float* __restrict__ ew,
                                               int* __restrict__ bcur,
                                               uint2* __restrict__ bin,
                                               uint4* __restrict__ ofl,
                                               int* __restrict__ oflcnt) {
  __shared__ __align__(16) char smem[48 * 1024];
  const int t = threadIdx.x;
  const int sub = blockIdx.x >> 1;

  if ((blockIdx.x & 1) == 0) {
    // ---------------- GEMM role ----------------
    unsigned short* As = (unsigned short*)smem;            // [128][64] 16 KB
    unsigned short* Bs = (unsigned short*)(smem + 16384);  // [256][64] 32 KB
    const int lane = t & 63;
    const int wid = t >> 6;          // 0..7
    const int wr = wid >> 1;         // 0..3  M quadrant (32 rows)
    const int wc = wid & 1;          // 0..1  N half (128 cols)
    const int m0 = sub * 128;

    f32x4 acc[2][8] = {};

    const int arow = t >> 2;         // 0..127
    const int akb = (t & 3) * 16;    // k offset
    int am = m0 + arow;
    if (am > N_NODES - 1) am = N_NODES - 1;
    const int sr = t >> 3;           // 0..63
    const int sc = t & 7;

    const int kg = lane >> 4;
    const int rl = lane & 15;

    for (int kt = 0; kt < 4; ++kt) {
      const int k0 = kt * 64;
#pragma unroll
      for (int i = 0; i < 4; ++i) {
        int r = i * 64 + sr;
        int cc = sc ^ (r & 7);
        const unsigned short* srcp = wt + (size_t)r * DDIM + k0 + cc * 8;
        __builtin_amdgcn_global_load_lds(
            (const __attribute__((address_space(1))) void*)srcp,
            (__attribute__((address_space(3))) void*)((char*)Bs + i * 8192 + t * 16),
            16, 0, 0);
      }
      {
        const float* xp = x + (size_t)am * DDIM + k0 + akb;
        f32x4 f0 = __builtin_nontemporal_load((const f32x4*)(xp + 0));
        f32x4 f1 = __builtin_nontemporal_load((const f32x4*)(xp + 4));
        f32x4 f2 = __builtin_nontemporal_load((const f32x4*)(xp + 8));
        f32x4 f3 = __builtin_nontemporal_load((const f32x4*)(xp + 12));
        uint4 p0, p1;
        p0.x = (unsigned)f32_to_bf16_rne(f0.x) | ((unsigned)f32_to_bf16_rne(f0.y) << 16);
        p0.y = (unsigned)f32_to_bf16_rne(f0.z) | ((unsigned)f32_to_bf16_rne(f0.w) << 16);
        p0.z = (unsigned)f32_to_bf16_rne(f1.x) | ((unsigned)f32_to_bf16_rne(f1.y) << 16);
        p0.w = (unsigned)f32_to_bf16_rne(f1.z) | ((unsigned)f32_to_bf16_rne(f1.w) << 16);
        p1.x = (unsigned)f32_to_bf16_rne(f2.x) | ((unsigned)f32_to_bf16_rne(f2.y) << 16);
        p1.y = (unsigned)f32_to_bf16_rne(f2.z) | ((unsigned)f32_to_bf16_rne(f2.w) << 16);
        p1.z = (unsigned)f32_to_bf16_rne(f3.x) | ((unsigned)f32_to_bf16_rne(f3.y) << 16);
        p1.w = (unsigned)f32_to_bf16_rne(f3.z) | ((unsigned)f32_to_bf16_rne(f3.w) << 16);
        int b0 = arow * 128 + akb * 2;
        int swz = (arow & 7) << 4;
        *(uint4*)((char*)As + (b0 ^ swz)) = p0;
        *(uint4*)((char*)As + ((b0 + 16) ^ swz)) = p1;
      }
      __syncthreads();

#pragma unroll
      for (int ks = 0; ks < 2; ++ks) {
        const int colbyte = ks * 64 + kg * 16;
        short8v af[2];
#pragma unroll
        for (int mi = 0; mi < 2; ++mi) {
          int row = wr * 32 + mi * 16 + rl;
          int bo = row * 128 + (colbyte ^ ((row & 7) << 4));
          af[mi] = *(const short8v*)((const char*)As + bo);
        }
#pragma unroll
        for (int ni = 0; ni < 8; ++ni) {
          int row = wc * 128 + ni * 16 + rl;
          int bo = row * 128 + (colbyte ^ ((row & 7) << 4));
          short8v bf = *(const short8v*)((const char*)Bs + bo);
          acc[0][ni] = __builtin_amdgcn_mfma_f32_16x16x32_bf16(af[0], bf, acc[0][ni], 0, 0, 0);
          acc[1][ni] = __builtin_amdgcn_mfma_f32_16x16x32_bf16(af[1], bf, acc[1][ni], 0, 0, 0);
        }
      }
      __syncthreads();
    }

    const int rbase = (lane >> 4) * 4;
    const int ncol = lane & 15;
#pragma unroll
    for (int mi = 0; mi < 2; ++mi) {
#pragma unroll
      for (int ni = 0; ni < 8; ++ni) {
        int n = wc * 128 + ni * 16 + ncol;
#pragma unroll
        for (int r = 0; r < 4; ++r) {
          int m = m0 + wr * 32 + mi * 16 + rbase + r;
          if (m < N_NODES)
            xw[(size_t)m * DDIM + n] = f32_to_bf16_rne(acc[mi][ni][r]);
        }
      }
    }
  } else {
    // ---------------- bin role ----------------
    int* hist = (int*)smem;   // counts, then cursors
    const int e0 = sub * BINBLK;
    int n = N_EDGES - e0;
    if (n > BINBLK) n = BINBLK;
    if (n < 0) n = 0;
    for (int i = t; i < NB; i += 512) hist[i] = 0;
    __syncthreads();
    int myd[8];
#pragma unroll
    for (int j = 0; j < 8; ++j) {
      int p = j * 512 + t;
      if (p < n) {
        myd[j] = __builtin_nontemporal_load(&edst[e0 + p]);
        atomicAdd(&hist[myd[j] >> 7], 1);
      } else {
        myd[j] = -1;
      }
    }
    __syncthreads();
    for (int i = t; i < NB; i += 512) {
      int h = hist[i];
      hist[i] = h ? atomicAdd(&bcur[i * 16], h) : 0;   // hist becomes cursor
    }
    __syncthreads();
#pragma unroll
    for (int j = 0; j < 8; ++j) {
      int p = j * 512 + t;
      if (p < n) {
        int d = myd[j];
        int bkt = d >> 7;
        int q = atomicAdd(&hist[bkt], 1);
        unsigned lo = ((unsigned)(d & 127) << 17) |
                      (unsigned)__builtin_nontemporal_load(&esrc[e0 + p]);
        unsigned hi = __float_as_uint(__builtin_nontemporal_load(&ew[e0 + p]));
        if (q < CAP) {
          unsigned long long rv = (unsigned long long)lo |
                                  ((unsigned long long)hi << 32);
          __builtin_nontemporal_store(
              rv, (unsigned long long*)&bin[(size_t)bkt * CAP + q]);
        } else {
          int op = atomicAdd(oflcnt, 1);
          if (op < OCAP)
            ofl[op] = make_uint4((unsigned)d, lo & 0x1FFFFu, hi, 0u);
        }
      }
    }
  }
}

// ---------------- per-bucket counting sort by dst_local (bin1 -> bin2) ------
// emits per-node segment offsets nof[b*NOFS + 0..128].

__global__ __launch_bounds__(512) void k_sort(const uint2* __restrict__ bin1,
                                              const int* __restrict__ bcur,
                                              uint2* __restrict__ bin2,
                                              int* __restrict__ nof) {
  __shared__ int lh[129];
  __shared__ int lc[128];
  const int b = blockIdx.x;
  const int t = threadIdx.x;
  int cnt = bcur[b * 16];
  if (cnt > CAP) cnt = CAP;
  if (t < 129) lh[t] = 0;
  __syncthreads();
  const int wid = t >> 6;
  const int lane = t & 63;
  uint2 rec[10];                 // ceil(CAP/512) = 10
  int nrec = 0;
#pragma unroll
  for (int j = 0; j < 10; ++j) {
    int p = t + j * 512;
    if (p < cnt) {
      unsigned long long rv = __builtin_nontemporal_load(
          (const unsigned long long*)&bin1[(size_t)b * CAP + p]);
      rec[j].x = (unsigned)rv;
      rec[j].y = (unsigned)(rv >> 32);
      atomicAdd(&lh[(rec[j].x >> 17) + 1], 1);
      nrec = j + 1;
    }
  }
  __syncthreads();
  if (wid == 0) {  // wave-parallel inclusive scan of lh[1..128]
    int v0 = lh[lane + 1];
    int v1 = lh[lane + 65];
#pragma unroll
    for (int d = 1; d < 64; d <<= 1) {
      int u = __shfl_up(v0, d);
      if (lane >= d) v0 += u;
    }
    int tot0 = __shfl(v0, 63);
#pragma unroll
    for (int d = 1; d < 64; d <<= 1) {
      int u = __shfl_up(v1, d);
      if (lane >= d) v1 += u;
    }
    v1 += tot0;
    lh[lane + 1] = v0;
    lh[lane + 65] = v1;
  }
  __syncthreads();
  if (t < 128) lc[t] = lh[t];
  __syncthreads();
#pragma unroll
  for (int j = 0; j < 10; ++j) {
    if (j < nrec) {
      int q = atomicAdd(&lc[rec[j].x >> 17], 1);
      bin2[(size_t)b * CAP + q] = rec[j];
    }
  }
  if (t < 129) nof[b * NOFS + t] = lh[t];
}

// ---------------- aggregate: LDS-resident sorted records, reg+shfl ----------
// grid (NB, 4): y = (chan half)*2 + (node half). 256 threads = 4 waves;
// wave handles 16 nodes; 16 lanes/edge x 16B (128 ch), 4 groups x 6-deep
// (fully named scalars; launch_bounds(256,6) gives VGPR headroom, no spill).
// z stores non-temporal so the 100 MB output stream doesn't evict xw from L3.

__global__ __launch_bounds__(256, 6) void k_baggr(const uint2* __restrict__ bin2,
                                                  const int* __restrict__ nof,
                                                  const unsigned short* __restrict__ xw,
                                                  const float* __restrict__ bias,
                                                  float* __restrict__ z) {
  __shared__ uint2 lsrt[LCAP];   // 19456 B
  const int b = blockIdx.x;
  const int h = blockIdx.y & 1;              // node half
  const int c128 = (blockIdx.y >> 1) * 128;  // channel half
  const int t = threadIdx.x;
  const int wid = t >> 6;
  const int lane = t & 63;
  const int g = lane >> 4;       // edge group 0..3
  const int l16 = lane & 15;
  const int gofs = c128 + l16 * 8;   // 8 channels, 16B
  const int* myof = nof + b * NOFS + h * 64;
  const uint2* mybin = bin2 + (size_t)b * CAP;

  const int base = myof[0];
  const int cnth = myof[64] - base;
  const uint2* rp;
  int rbase;
  if (cnth <= LCAP) {
    for (int i = t; i < cnth; i += 256) lsrt[i] = mybin[base + i];
    rp = (const uint2*)lsrt;    // generic pointer into LDS
    rbase = base;
  } else {
    rp = mybin;                 // fallback: statistically unreachable
    rbase = 0;
  }
  __syncthreads();

  float4 bv = make_float4(0.f, 0.f, 0.f, 0.f);
  if (g < 2) bv = *(const float4*)(bias + gofs + g * 4);

#pragma unroll 1
  for (int ii = 0; ii < 16; ++ii) {
    const int i = wid * 16 + ii;               // node within half (0..63)
    const int node = (b << 7) + h * 64 + i;
    if (node >= N_NODES) break;
    const int s = myof[i] - rbase;
    const int e2 = myof[i + 1] - rbase;
    float a0 = 0.f, a1 = 0.f, a2 = 0.f, a3 = 0.f;
    float a4 = 0.f, a5 = 0.f, a6 = 0.f, a7 = 0.f;
#pragma unroll 1
    for (int p = s; p < e2; p += 24) {
      unsigned sx0, sx1, sx2, sx3, sx4, sx5;
      float w0, w1, w2, w3, w4, w5;
      {
        int i0 = p + 0 * 4 + g; bool k0 = i0 < e2; uint2 r = rp[k0 ? i0 : s];
        sx0 = r.x & 0x1FFFFu; w0 = k0 ? __uint_as_float(r.y) : 0.f;
      }
      {
        int i1 = p + 1 * 4 + g; bool k1 = i1 < e2; uint2 r = rp[k1 ? i1 : s];
        sx1 = r.x & 0x1FFFFu; w1 = k1 ? __uint_as_float(r.y) : 0.f;
      }
      {
        int i2 = p + 2 * 4 + g; bool k2 = i2 < e2; uint2 r = rp[k2 ? i2 : s];
        sx2 = r.x & 0x1FFFFu; w2 = k2 ? __uint_as_float(r.y) : 0.f;
      }
      {
        int i3 = p + 3 * 4 + g; bool k3 = i3 < e2; uint2 r = rp[k3 ? i3 : s];
        sx3 = r.x & 0x1FFFFu; w3 = k3 ? __uint_as_float(r.y) : 0.f;
      }
      {
        int i4 = p + 4 * 4 + g; bool k4 = i4 < e2; uint2 r = rp[k4 ? i4 : s];
        sx4 = r.x & 0x1FFFFu; w4 = k4 ? __uint_as_float(r.y) : 0.f;
      }
      {
        int i5 = p + 5 * 4 + g; bool k5 = i5 < e2; uint2 r = rp[k5 ? i5 : s];
        sx5 = r.x & 0x1FFFFu; w5 = k5 ? __uint_as_float(r.y) : 0.f;
      }
      uint4 v0 = *(const uint4*)(xw + ((sx0 << 8) + gofs));
      uint4 v1 = *(const uint4*)(xw + ((sx1 << 8) + gofs));
      uint4 v2 = *(const uint4*)(xw + ((sx2 << 8) + gofs));
      uint4 v3 = *(const uint4*)(xw + ((sx3 << 8) + gofs));
      uint4 v4 = *(const uint4*)(xw + ((sx4 << 8) + gofs));
      uint4 v5 = *(const uint4*)(xw + ((sx5 << 8) + gofs));
      a0 += w0 * bfLO(v0.x); a1 += w0 * bfHI(v0.x);
      a2 += w0 * bfLO(v0.y); a3 += w0 * bfHI(v0.y);
      a4 += w0 * bfLO(v0.z); a5 += w0 * bfHI(v0.z);
      a6 += w0 * bfLO(v0.w); a7 += w0 * bfHI(v0.w);
      a0 += w1 * bfLO(v1.x); a1 += w1 * bfHI(v1.x);
      a2 += w1 * bfLO(v1.y); a3 += w1 * bfHI(v1.y);
      a4 += w1 * bfLO(v1.z); a5 += w1 * bfHI(v1.z);
      a6 += w1 * bfLO(v1.w); a7 += w1 * bfHI(v1.w);
      a0 += w2 * bfLO(v2.x); a1 += w2 * bfHI(v2.x);
      a2 += w2 * bfLO(v2.y); a3 += w2 * bfHI(v2.y);
      a4 += w2 * bfLO(v2.z); a5 += w2 * bfHI(v2.z);
      a6 += w2 * bfLO(v2.w); a7 += w2 * bfHI(v2.w);
      a0 += w3 * bfLO(v3.x); a1 += w3 * bfHI(v3.x);
      a2 += w3 * bfLO(v3.y); a3 += w3 * bfHI(v3.y);
      a4 += w3 * bfLO(v3.z); a5 += w3 * bfHI(v3.z);
      a6 += w3 * bfLO(v3.w); a7 += w3 * bfHI(v3.w);
      a0 += w4 * bfLO(v4.x); a1 += w4 * bfHI(v4.x);
      a2 += w4 * bfLO(v4.y); a3 += w4 * bfHI(v4.y);
      a4 += w4 * bfLO(v4.z); a5 += w4 * bfHI(v4.z);
      a6 += w4 * bfLO(v4.w); a7 += w4 * bfHI(v4.w);
      a0 += w5 * bfLO(v5.x); a1 += w5 * bfHI(v5.x);
      a2 += w5 * bfLO(v5.y); a3 += w5 * bfHI(v5.y);
      a4 += w5 * bfLO(v5.z); a5 += w5 * bfHI(v5.z);
      a6 += w5 * bfLO(v5.w); a7 += w5 * bfHI(v5.w);
    }
    a0 += __shfl_xor(a0, 16); a0 += __shfl_xor(a0, 32);
    a1 += __shfl_xor(a1, 16); a1 += __shfl_xor(a1, 32);
    a2 += __shfl_xor(a2, 16); a2 += __shfl_xor(a2, 32);
    a3 += __shfl_xor(a3, 16); a3 += __shfl_xor(a3, 32);
    a4 += __shfl_xor(a4, 16); a4 += __shfl_xor(a4, 32);
    a5 += __shfl_xor(a5, 16); a5 += __shfl_xor(a5, 32);
    a6 += __shfl_xor(a6, 16); a6 += __shfl_xor(a6, 32);
    a7 += __shfl_xor(a7, 16); a7 += __shfl_xor(a7, 32);
    if (g < 2) {
      f32x4 o;
      if (g) {
        o.x = a4 + bv.x; o.y = a5 + bv.y; o.z = a6 + bv.z; o.w = a7 + bv.w;
      } else {
        o.x = a0 + bv.x; o.y = a1 + bv.y; o.z = a2 + bv.z; o.w = a3 + bv.w;
      }
      __builtin_nontemporal_store(
          o, (f32x4*)(z + (size_t)node * DDIM + gofs + g * 4));
    }
  }
}

// ---------------- overflow fixup (normally empty) ----------------

__global__ __launch_bounds__(256) void k_ofl(const uint4* __restrict__ ofl,
                                             const int* __restrict__ oflcnt,
                                             const unsigned short* __restrict__ xw,
                                             float* __restrict__ z) {
  int n = oflcnt[0];
  if (n > OCAP) n = OCAP;
  for (int r = blockIdx.x; r < n; r += gridDim.x) {
    uint4 rec = ofl[r];
    float wgt = __uint_as_float(rec.z);
    int c = threadIdx.x;
    float v = bf16_to_f32(xw[(size_t)rec.y * DDIM + c]);
    atomicAdd(&z[(size_t)rec.x * DDIM + c], wgt * v);
  }
}

extern "C" void kernel_launch(void* const* d_in, const int* in_sizes, int n_in,
                              void* d_out, int out_size, void* d_ws, size_t ws_size,
                              hipStream_t stream) {
  const float* x = (const float*)d_in[0];
  const float* w = (const float*)d_in[1];
  const float* bias = (const float*)d_in[2];
  const int* esrc = (const int*)d_in[3];
  const int* edst = (const int*)d_in[4];
  const float* ew = (const float*)d_in[5];
  float* z = (float*)d_out;

  char* ws = (char*)d_ws;
  size_t off = 0;
  unsigned short* xw = (unsigned short*)(ws + off);
  off += (size_t)N_NODES * DDIM * 2;                        // 51.2 MB
  unsigned short* wt = (unsigned short*)(ws + off);
  off += (size_t)DDIM * DDIM * 2;                           // 128 KB
  int* bcur = (int*)(ws + off);
  off += (size_t)NB * 16 * 4;                               // 50 KB (line-padded cursors)
  int* oflcnt = (int*)(ws + off);
  off += 256;
  int* nof = (int*)(ws + off);
  off += (size_t)NB * NOFS * 4;                             // 413 KB
  uint4* ofl = (uint4*)(ws + off);
  off += (size_t)OCAP * 16;                                 // 1 MB
  uint2* bin1 = (uint2*)(ws + off);
  off += (size_t)NB * CAP * 8;                              // 30 MB
  uint2* bin2 = (uint2*)(ws + off);
  off += (size_t)NB * CAP * 8;                              // 30 MB
  // total ~113 MB

  hipMemsetAsync(bcur, 0, (size_t)NB * 16 * 4 + 256, stream);  // bcur + oflcnt
  k_cvtW<<<(DDIM * DDIM + 255) / 256, 256, 0, stream>>>(w, wt);
  k_gb<<<2 * NB, 512, 0, stream>>>(x, wt, xw, esrc, edst, ew, bcur, bin1, ofl, oflcnt);
  k_sort<<<NB, 512, 0, stream>>>(bin1, bcur, bin2, nof);
  dim3 ag(NB, 4);
  k_baggr<<<ag, 256, 0, stream>>>(bin2, nof, xw, bias, z);
  k_ofl<<<64, 256, 0, stream>>>(ofl, oflcnt, xw, z);
}

// Round 17
// 371.173 us; speedup vs baseline: 1.1447x; 1.1447x over previous
//
#include <hip/hip_runtime.h>
#include <hip/hip_bf16.h>
#include <stdint.h>

#define N_NODES 100000
#define N_EDGES 3200000
#define DDIM 256
#define NB 782        // ceil(100000 / 128) buckets of 128 dst nodes
#define CAP 4800      // per-bucket slot capacity (mean 4092, sd 64; 11 sigma)
#define BINBLK 4096   // edges per bin role-block
#define OCAP 65536    // overflow list capacity (statistically unreachable)
#define NOFS 132      // per-bucket offset-row stride (ints)
#define LCAP 2432     // per-half LDS record capacity (mean 2046, sd 45; 8.5 sigma)

typedef __attribute__((ext_vector_type(8))) short short8v;
typedef __attribute__((ext_vector_type(4))) float f32x4;

static __device__ __forceinline__ unsigned short f32_to_bf16_rne(float f) {
  unsigned u = __float_as_uint(f);
  unsigned rounded = u + 0x7FFFu + ((u >> 16) & 1u);
  return (unsigned short)(rounded >> 16);
}

static __device__ __forceinline__ float bf16_to_f32(unsigned short h) {
  return __uint_as_float((unsigned)h << 16);
}

static __device__ __forceinline__ float bfLO(unsigned v) { return __uint_as_float(v << 16); }
static __device__ __forceinline__ float bfHI(unsigned v) { return __uint_as_float(v & 0xFFFF0000u); }

// ---------------- Wt[n][k] = W[k][n], bf16 ----------------

__global__ __launch_bounds__(256) void k_cvtW(const float* __restrict__ w,
                                              unsigned short* __restrict__ wt) {
  int i = blockIdx.x * blockDim.x + threadIdx.x;
  int k = i >> 8;
  int n = i & 255;
  wt[(size_t)n * DDIM + k] = f32_to_bf16_rne(w[(size_t)k * DDIM + n]);
}

// ---------------- fused: GEMM blocks (bid&1==0) + bin blocks (bid&1==1) ----
// GEMM: XW = X @ W (bf16 MFMA), fused f32->bf16 A-stage, tile 128x256, BK=64.
// bin: block-level LDS binning into fixed-stride bucket regions.

__global__ __launch_bounds__(512, 2) void k_gb(const float* __restrict__ x,
                                               const unsigned short* __restrict__ wt,
                                               unsigned short* __restrict__ xw,
                                               const int* __restrict__ esrc,
                                               const int* __restrict__ edst,
                                               const float* __restrict__ ew,
                                               int* __restrict__ bcur,
                                               uint2* __restrict__ bin,
                                               uint4* __restrict__ ofl,
                                               int* __restrict__ oflcnt) {
  __shared__ __align__(16) char smem[48 * 1024];
  const int t = threadIdx.x;
  const int sub = blockIdx.x >> 1;

  if ((blockIdx.x & 1) == 0) {
    // ---------------- GEMM role ----------------
    unsigned short* As = (unsigned short*)smem;            // [128][64] 16 KB
    unsigned short* Bs = (unsigned short*)(smem + 16384);  // [256][64] 32 KB
    const int lane = t & 63;
    const int wid = t >> 6;          // 0..7
    const int wr = wid >> 1;         // 0..3  M quadrant (32 rows)
    const int wc = wid & 1;          // 0..1  N half (128 cols)
    const int m0 = sub * 128;

    f32x4 acc[2][8] = {};

    const int arow = t >> 2;         // 0..127
    const int akb = (t & 3) * 16;    // k offset
    int am = m0 + arow;
    if (am > N_NODES - 1) am = N_NODES - 1;
    const int sr = t >> 3;           // 0..63
    const int sc = t & 7;

    const int kg = lane >> 4;
    const int rl = lane & 15;

    for (int kt = 0; kt < 4; ++kt) {
      const int k0 = kt * 64;
#pragma unroll
      for (int i = 0; i < 4; ++i) {
        int r = i * 64 + sr;
        int cc = sc ^ (r & 7);
        const unsigned short* srcp = wt + (size_t)r * DDIM + k0 + cc * 8;
        __builtin_amdgcn_global_load_lds(
            (const __attribute__((address_space(1))) void*)srcp,
            (__attribute__((address_space(3))) void*)((char*)Bs + i * 8192 + t * 16),
            16, 0, 0);
      }
      {
        const float* xp = x + (size_t)am * DDIM + k0 + akb;
        float4 f0 = *(const float4*)(xp + 0);
        float4 f1 = *(const float4*)(xp + 4);
        float4 f2 = *(const float4*)(xp + 8);
        float4 f3 = *(const float4*)(xp + 12);
        uint4 p0, p1;
        p0.x = (unsigned)f32_to_bf16_rne(f0.x) | ((unsigned)f32_to_bf16_rne(f0.y) << 16);
        p0.y = (unsigned)f32_to_bf16_rne(f0.z) | ((unsigned)f32_to_bf16_rne(f0.w) << 16);
        p0.z = (unsigned)f32_to_bf16_rne(f1.x) | ((unsigned)f32_to_bf16_rne(f1.y) << 16);
        p0.w = (unsigned)f32_to_bf16_rne(f1.z) | ((unsigned)f32_to_bf16_rne(f1.w) << 16);
        p1.x = (unsigned)f32_to_bf16_rne(f2.x) | ((unsigned)f32_to_bf16_rne(f2.y) << 16);
        p1.y = (unsigned)f32_to_bf16_rne(f2.z) | ((unsigned)f32_to_bf16_rne(f2.w) << 16);
        p1.z = (unsigned)f32_to_bf16_rne(f3.x) | ((unsigned)f32_to_bf16_rne(f3.y) << 16);
        p1.w = (unsigned)f32_to_bf16_rne(f3.z) | ((unsigned)f32_to_bf16_rne(f3.w) << 16);
        int b0 = arow * 128 + akb * 2;
        int swz = (arow & 7) << 4;
        *(uint4*)((char*)As + (b0 ^ swz)) = p0;
        *(uint4*)((char*)As + ((b0 + 16) ^ swz)) = p1;
      }
      __syncthreads();

#pragma unroll
      for (int ks = 0; ks < 2; ++ks) {
        const int colbyte = ks * 64 + kg * 16;
        short8v af[2];
#pragma unroll
        for (int mi = 0; mi < 2; ++mi) {
          int row = wr * 32 + mi * 16 + rl;
          int bo = row * 128 + (colbyte ^ ((row & 7) << 4));
          af[mi] = *(const short8v*)((const char*)As + bo);
        }
#pragma unroll
        for (int ni = 0; ni < 8; ++ni) {
          int row = wc * 128 + ni * 16 + rl;
          int bo = row * 128 + (colbyte ^ ((row & 7) << 4));
          short8v bf = *(const short8v*)((const char*)Bs + bo);
          acc[0][ni] = __builtin_amdgcn_mfma_f32_16x16x32_bf16(af[0], bf, acc[0][ni], 0, 0, 0);
          acc[1][ni] = __builtin_amdgcn_mfma_f32_16x16x32_bf16(af[1], bf, acc[1][ni], 0, 0, 0);
        }
      }
      __syncthreads();
    }

    const int rbase = (lane >> 4) * 4;
    const int ncol = lane & 15;
#pragma unroll
    for (int mi = 0; mi < 2; ++mi) {
#pragma unroll
      for (int ni = 0; ni < 8; ++ni) {
        int n = wc * 128 + ni * 16 + ncol;
#pragma unroll
        for (int r = 0; r < 4; ++r) {
          int m = m0 + wr * 32 + mi * 16 + rbase + r;
          if (m < N_NODES)
            xw[(size_t)m * DDIM + n] = f32_to_bf16_rne(acc[mi][ni][r]);
        }
      }
    }
  } else {
    // ---------------- bin role ----------------
    int* hist = (int*)smem;   // counts, then cursors
    const int e0 = sub * BINBLK;
    int n = N_EDGES - e0;
    if (n > BINBLK) n = BINBLK;
    if (n < 0) n = 0;
    for (int i = t; i < NB; i += 512) hist[i] = 0;
    __syncthreads();
    int myd[8];
#pragma unroll
    for (int j = 0; j < 8; ++j) {
      int p = j * 512 + t;
      if (p < n) {
        myd[j] = edst[e0 + p];
        atomicAdd(&hist[myd[j] >> 7], 1);
      } else {
        myd[j] = -1;
      }
    }
    __syncthreads();
    for (int i = t; i < NB; i += 512) {
      int h = hist[i];
      hist[i] = h ? atomicAdd(&bcur[i * 16], h) : 0;   // hist becomes cursor
    }
    __syncthreads();
#pragma unroll
    for (int j = 0; j < 8; ++j) {
      int p = j * 512 + t;
      if (p < n) {
        int d = myd[j];
        int bkt = d >> 7;
        int q = atomicAdd(&hist[bkt], 1);
        if (q < CAP) {
          bin[(size_t)bkt * CAP + q] =
              make_uint2(((unsigned)(d & 127) << 17) | (unsigned)esrc[e0 + p],
                         __float_as_uint(ew[e0 + p]));
        } else {
          int op = atomicAdd(oflcnt, 1);
          if (op < OCAP)
            ofl[op] = make_uint4((unsigned)d, (unsigned)esrc[e0 + p],
                                 __float_as_uint(ew[e0 + p]), 0u);
        }
      }
    }
  }
}

// ---------------- per-bucket counting sort by dst_local (bin1 -> bin2) ------
// emits per-node segment offsets nof[b*NOFS + 0..128].

__global__ __launch_bounds__(512) void k_sort(const uint2* __restrict__ bin1,
                                              const int* __restrict__ bcur,
                                              uint2* __restrict__ bin2,
                                              int* __restrict__ nof) {
  __shared__ int lh[129];
  __shared__ int lc[128];
  const int b = blockIdx.x;
  const int t = threadIdx.x;
  int cnt = bcur[b * 16];
  if (cnt > CAP) cnt = CAP;
  if (t < 129) lh[t] = 0;
  __syncthreads();
  const int wid = t >> 6;
  const int lane = t & 63;
  uint2 rec[10];                 // ceil(CAP/512) = 10
  int nrec = 0;
#pragma unroll
  for (int j = 0; j < 10; ++j) {
    int p = t + j * 512;
    if (p < cnt) {
      rec[j] = bin1[(size_t)b * CAP + p];
      atomicAdd(&lh[(rec[j].x >> 17) + 1], 1);
      nrec = j + 1;
    }
  }
  __syncthreads();
  if (wid == 0) {  // wave-parallel inclusive scan of lh[1..128]
    int v0 = lh[lane + 1];
    int v1 = lh[lane + 65];
#pragma unroll
    for (int d = 1; d < 64; d <<= 1) {
      int u = __shfl_up(v0, d);
      if (lane >= d) v0 += u;
    }
    int tot0 = __shfl(v0, 63);
#pragma unroll
    for (int d = 1; d < 64; d <<= 1) {
      int u = __shfl_up(v1, d);
      if (lane >= d) v1 += u;
    }
    v1 += tot0;
    lh[lane + 1] = v0;
    lh[lane + 65] = v1;
  }
  __syncthreads();
  if (t < 128) lc[t] = lh[t];
  __syncthreads();
#pragma unroll
  for (int j = 0; j < 10; ++j) {
    if (j < nrec) {
      int q = atomicAdd(&lc[rec[j].x >> 17], 1);
      bin2[(size_t)b * CAP + q] = rec[j];
    }
  }
  if (t < 129) nof[b * NOFS + t] = lh[t];
}

// ---------------- aggregate: LDS-resident sorted records, reg+shfl ----------
// grid (NB, 4): y = (chan half)*2 + (node half). 256 threads = 4 waves;
// wave handles 16 nodes; 16 lanes/edge x 16B (128 ch), 4 groups x 6-deep
// (fully named scalars; launch_bounds(256,6) gives VGPR headroom, no spill).

__global__ __launch_bounds__(256, 6) void k_baggr(const uint2* __restrict__ bin2,
                                                  const int* __restrict__ nof,
                                                  const unsigned short* __restrict__ xw,
                                                  const float* __restrict__ bias,
                                                  float* __restrict__ z) {
  __shared__ uint2 lsrt[LCAP];   // 19456 B
  const int b = blockIdx.x;
  const int h = blockIdx.y & 1;              // node half
  const int c128 = (blockIdx.y >> 1) * 128;  // channel half
  const int t = threadIdx.x;
  const int wid = t >> 6;
  const int lane = t & 63;
  const int g = lane >> 4;       // edge group 0..3
  const int l16 = lane & 15;
  const int gofs = c128 + l16 * 8;   // 8 channels, 16B
  const int* myof = nof + b * NOFS + h * 64;
  const uint2* mybin = bin2 + (size_t)b * CAP;

  const int base = myof[0];
  const int cnth = myof[64] - base;
  const uint2* rp;
  int rbase;
  if (cnth <= LCAP) {
    for (int i = t; i < cnth; i += 256) lsrt[i] = mybin[base + i];
    rp = (const uint2*)lsrt;    // generic pointer into LDS
    rbase = base;
  } else {
    rp = mybin;                 // fallback: statistically unreachable
    rbase = 0;
  }
  __syncthreads();

  float4 bv = make_float4(0.f, 0.f, 0.f, 0.f);
  if (g < 2) bv = *(const float4*)(bias + gofs + g * 4);

#pragma unroll 1
  for (int ii = 0; ii < 16; ++ii) {
    const int i = wid * 16 + ii;               // node within half (0..63)
    const int node = (b << 7) + h * 64 + i;
    if (node >= N_NODES) break;
    const int s = myof[i] - rbase;
    const int e2 = myof[i + 1] - rbase;
    float a0 = 0.f, a1 = 0.f, a2 = 0.f, a3 = 0.f;
    float a4 = 0.f, a5 = 0.f, a6 = 0.f, a7 = 0.f;
#pragma unroll 1
    for (int p = s; p < e2; p += 24) {
      unsigned sx0, sx1, sx2, sx3, sx4, sx5;
      float w0, w1, w2, w3, w4, w5;
      {
        int i0 = p + 0 * 4 + g; bool k0 = i0 < e2; uint2 r = rp[k0 ? i0 : s];
        sx0 = r.x & 0x1FFFFu; w0 = k0 ? __uint_as_float(r.y) : 0.f;
      }
      {
        int i1 = p + 1 * 4 + g; bool k1 = i1 < e2; uint2 r = rp[k1 ? i1 : s];
        sx1 = r.x & 0x1FFFFu; w1 = k1 ? __uint_as_float(r.y) : 0.f;
      }
      {
        int i2 = p + 2 * 4 + g; bool k2 = i2 < e2; uint2 r = rp[k2 ? i2 : s];
        sx2 = r.x & 0x1FFFFu; w2 = k2 ? __uint_as_float(r.y) : 0.f;
      }
      {
        int i3 = p + 3 * 4 + g; bool k3 = i3 < e2; uint2 r = rp[k3 ? i3 : s];
        sx3 = r.x & 0x1FFFFu; w3 = k3 ? __uint_as_float(r.y) : 0.f;
      }
      {
        int i4 = p + 4 * 4 + g; bool k4 = i4 < e2; uint2 r = rp[k4 ? i4 : s];
        sx4 = r.x & 0x1FFFFu; w4 = k4 ? __uint_as_float(r.y) : 0.f;
      }
      {
        int i5 = p + 5 * 4 + g; bool k5 = i5 < e2; uint2 r = rp[k5 ? i5 : s];
        sx5 = r.x & 0x1FFFFu; w5 = k5 ? __uint_as_float(r.y) : 0.f;
      }
      uint4 v0 = *(const uint4*)(xw + ((sx0 << 8) + gofs));
      uint4 v1 = *(const uint4*)(xw + ((sx1 << 8) + gofs));
      uint4 v2 = *(const uint4*)(xw + ((sx2 << 8) + gofs));
      uint4 v3 = *(const uint4*)(xw + ((sx3 << 8) + gofs));
      uint4 v4 = *(const uint4*)(xw + ((sx4 << 8) + gofs));
      uint4 v5 = *(const uint4*)(xw + ((sx5 << 8) + gofs));
      a0 += w0 * bfLO(v0.x); a1 += w0 * bfHI(v0.x);
      a2 += w0 * bfLO(v0.y); a3 += w0 * bfHI(v0.y);
      a4 += w0 * bfLO(v0.z); a5 += w0 * bfHI(v0.z);
      a6 += w0 * bfLO(v0.w); a7 += w0 * bfHI(v0.w);
      a0 += w1 * bfLO(v1.x); a1 += w1 * bfHI(v1.x);
      a2 += w1 * bfLO(v1.y); a3 += w1 * bfHI(v1.y);
      a4 += w1 * bfLO(v1.z); a5 += w1 * bfHI(v1.z);
      a6 += w1 * bfLO(v1.w); a7 += w1 * bfHI(v1.w);
      a0 += w2 * bfLO(v2.x); a1 += w2 * bfHI(v2.x);
      a2 += w2 * bfLO(v2.y); a3 += w2 * bfHI(v2.y);
      a4 += w2 * bfLO(v2.z); a5 += w2 * bfHI(v2.z);
      a6 += w2 * bfLO(v2.w); a7 += w2 * bfHI(v2.w);
      a0 += w3 * bfLO(v3.x); a1 += w3 * bfHI(v3.x);
      a2 += w3 * bfLO(v3.y); a3 += w3 * bfHI(v3.y);
      a4 += w3 * bfLO(v3.z); a5 += w3 * bfHI(v3.z);
      a6 += w3 * bfLO(v3.w); a7 += w3 * bfHI(v3.w);
      a0 += w4 * bfLO(v4.x); a1 += w4 * bfHI(v4.x);
      a2 += w4 * bfLO(v4.y); a3 += w4 * bfHI(v4.y);
      a4 += w4 * bfLO(v4.z); a5 += w4 * bfHI(v4.z);
      a6 += w4 * bfLO(v4.w); a7 += w4 * bfHI(v4.w);
      a0 += w5 * bfLO(v5.x); a1 += w5 * bfHI(v5.x);
      a2 += w5 * bfLO(v5.y); a3 += w5 * bfHI(v5.y);
      a4 += w5 * bfLO(v5.z); a5 += w5 * bfHI(v5.z);
      a6 += w5 * bfLO(v5.w); a7 += w5 * bfHI(v5.w);
    }
    a0 += __shfl_xor(a0, 16); a0 += __shfl_xor(a0, 32);
    a1 += __shfl_xor(a1, 16); a1 += __shfl_xor(a1, 32);
    a2 += __shfl_xor(a2, 16); a2 += __shfl_xor(a2, 32);
    a3 += __shfl_xor(a3, 16); a3 += __shfl_xor(a3, 32);
    a4 += __shfl_xor(a4, 16); a4 += __shfl_xor(a4, 32);
    a5 += __shfl_xor(a5, 16); a5 += __shfl_xor(a5, 32);
    a6 += __shfl_xor(a6, 16); a6 += __shfl_xor(a6, 32);
    a7 += __shfl_xor(a7, 16); a7 += __shfl_xor(a7, 32);
    if (g < 2) {
      float4 o = g ? make_float4(a4 + bv.x, a5 + bv.y, a6 + bv.z, a7 + bv.w)
                   : make_float4(a0 + bv.x, a1 + bv.y, a2 + bv.z, a3 + bv.w);
      *(float4*)(z + (size_t)node * DDIM + gofs + g * 4) = o;
    }
  }
}

// ---------------- overflow fixup (normally empty) ----------------

__global__ __launch_bounds__(256) void k_ofl(const uint4* __restrict__ ofl,
                                             const int* __restrict__ oflcnt,
                                             const unsigned short* __restrict__ xw,
                                             float* __restrict__ z) {
  int n = oflcnt[0];
  if (n > OCAP) n = OCAP;
  for (int r = blockIdx.x; r < n; r += gridDim.x) {
    uint4 rec = ofl[r];
    float wgt = __uint_as_float(rec.z);
    int c = threadIdx.x;
    float v = bf16_to_f32(xw[(size_t)rec.y * DDIM + c]);
    atomicAdd(&z[(size_t)rec.x * DDIM + c], wgt * v);
  }
}

extern "C" void kernel_launch(void* const* d_in, const int* in_sizes, int n_in,
                              void* d_out, int out_size, void* d_ws, size_t ws_size,
                              hipStream_t stream) {
  const float* x = (const float*)d_in[0];
  const float* w = (const float*)d_in[1];
  const float* bias = (const float*)d_in[2];
  const int* esrc = (const int*)d_in[3];
  const int* edst = (const int*)d_in[4];
  const float* ew = (const float*)d_in[5];
  float* z = (float*)d_out;

  char* ws = (char*)d_ws;
  size_t off = 0;
  unsigned short* xw = (unsigned short*)(ws + off);
  off += (size_t)N_NODES * DDIM * 2;                        // 51.2 MB
  unsigned short* wt = (unsigned short*)(ws + off);
  off += (size_t)DDIM * DDIM * 2;                           // 128 KB
  int* bcur = (int*)(ws + off);
  off += (size_t)NB * 16 * 4;                               // 50 KB (line-padded cursors)
  int* oflcnt = (int*)(ws + off);
  off += 256;
  int* nof = (int*)(ws + off);
  off += (size_t)NB * NOFS * 4;                             // 413 KB
  uint4* ofl = (uint4*)(ws + off);
  off += (size_t)OCAP * 16;                                 // 1 MB
  uint2* bin1 = (uint2*)(ws + off);
  off += (size_t)NB * CAP * 8;                              // 30 MB
  uint2* bin2 = (uint2*)(ws + off);
  off += (size_t)NB * CAP * 8;                              // 30 MB
  // total ~113 MB

  hipMemsetAsync(bcur, 0, (size_t)NB * 16 * 4 + 256, stream);  // bcur + oflcnt
  k_cvtW<<<(DDIM * DDIM + 255) / 256, 256, 0, stream>>>(w, wt);
  k_gb<<<2 * NB, 512, 0, stream>>>(x, wt, xw, esrc, edst, ew, bcur, bin1, ofl, oflcnt);
  k_sort<<<NB, 512, 0, stream>>>(bin1, bcur, bin2, nof);
  dim3 ag(NB, 4);
  k_baggr<<<ag, 256, 0, stream>>>(bin2, nof, xw, bias, z);
  k_ofl<<<64, 256, 0, stream>>>(ofl, oflcnt, xw, z);
}